// Round 11
// baseline (102.340 us; speedup 1.0000x reference)
//
#include <hip/hip_runtime.h>

#define CROP_H 14
#define CROP_W 14
#define IMG_B 8
#define IMG_C 256
#define IMG_H 100
#define IMG_W 152
#define NBOX 1000
#define PLANE (IMG_H * IMG_W)                 // 15200
#define POS (CROP_H * CROP_W)                 // 196
#define PAIRS (POS / 2)                       // 98 x-pair tasks per (box)
#define OUT_PER_BOX (IMG_C * POS)             // 50176
#define BOXCAP 64                             // boxes per param chunk
#define NCP (IMG_C / 2)                       // 128 channel pairs
#define CG 32                                 // fallback path
#define NCG (IMG_C / CG)

typedef float f2u __attribute__((ext_vector_type(2), aligned(8)));
typedef float f4u __attribute__((ext_vector_type(4), aligned(16)));

// ---------------------------------------------------------------------------
// Kernel A: stable counting-sort of boxes by box_ind -> perm + per-image
// offsets. Deterministic (atomicOr order-independent, popcount ranks).
// ---------------------------------------------------------------------------
__global__ __launch_bounds__(1024) void sort_boxes_kernel(
    const int* __restrict__ box_ind,
    int* __restrict__ perm,
    int* __restrict__ offsets)            // [IMG_B + 1]
{
    __shared__ unsigned s_mask[IMG_B][32];
    __shared__ int s_tot[IMG_B];
    const int tid = threadIdx.x;

    if (tid < IMG_B * 32) ((unsigned*)s_mask)[tid] = 0u;
    __syncthreads();

    int key = 0;
    if (tid < NBOX) {
        key = box_ind[tid];
        atomicOr(&s_mask[key][tid >> 5], 1u << (tid & 31));
    }
    __syncthreads();

    if (tid < IMG_B) {
        int t = 0;
        #pragma unroll
        for (int w = 0; w < 32; ++w) t += __popc(s_mask[tid][w]);
        s_tot[tid] = t;
    }
    __syncthreads();

    if (tid == 0) {
        int acc = 0;
        #pragma unroll
        for (int k = 0; k < IMG_B; ++k) { offsets[k] = acc; acc += s_tot[k]; }
        offsets[IMG_B] = acc;
    }

    if (tid < NBOX) {
        int base = 0;
        #pragma unroll
        for (int k = 0; k < IMG_B; ++k) base += (k < key) ? s_tot[k] : 0;
        const int w = tid >> 5, b = tid & 31;
        int r = __popc(s_mask[key][w] & ((b == 0) ? 0u : ((1u << b) - 1u)));
        for (int ww = 0; ww < w; ++ww) r += __popc(s_mask[key][ww]);
        perm[base + r] = tid;
    }
}

// ---------------------------------------------------------------------------
// Kernel B: TWO planes in LDS, 4 outputs per thread (x-pair x channel-pair).
// Block = (channel-pair, image). Stage 2 contiguous planes (121.6 KB) once,
// coalesced -- each plane read from HBM exactly once device-wide. Per-box
// row state (f2u) and column-pair state (f4u) precomputed per chunk. Thread
// task = (box, y, x-pair): index math / pack reads / extracts / clamp masks
// computed ONCE, then reused for both channels: 2 x {4 plane reads (fusable
// ds_read2), 2 lerps, 1 float2 store}.
// ---------------------------------------------------------------------------
__global__ __launch_bounds__(1024, 4) void CropAndResize_16630113370849_kernel(
    const float* __restrict__ image,
    const float* __restrict__ boxes,
    const int* __restrict__ perm,
    const int* __restrict__ offsets,
    float* __restrict__ out)
{
    __shared__ __align__(16) float s_plane[2 * PLANE];   // 121,600 B
    __shared__ f2u s_row[BOXCAP * CROP_H];     // {bits(r0*152|sely<<14|vy<<15), yw}
    __shared__ f4u s_colp[BOXCAP * 7];         // {bits0, xw0, bits1, xw1}
    __shared__ unsigned s_ob[BOXCAP];          // n * OUT_PER_BOX

    const int cp  = blockIdx.x;                // channel pair 0..127
    const int b   = blockIdx.y;                // image 0..7
    const int tid = threadIdx.x;

    // stage both planes: 30400 floats = 7600 float4, contiguous, coalesced
    {
        const float4* __restrict__ src =
            (const float4*)(image + ((size_t)b * IMG_C + 2 * cp) * PLANE);
        float4* dst = (float4*)s_plane;
        #pragma unroll
        for (int i = 0; i < 8; ++i) {
            const int e = i * 1024 + tid;
            if (e < (2 * PLANE) / 4) dst[e] = src[e];
        }
    }

    const int s0 = offsets[b], s1 = offsets[b + 1];
    const unsigned cbase = (unsigned)(2 * cp * POS);

    for (int ck = s0; ck < s1; ck += BOXCAP) {
        const int cnt = min(BOXCAP, s1 - ck);

        __syncthreads();   // planes ready (1st iter) / prev chunk readers done

        // setup: cnt*21 tasks (14 rows + 7 col-pairs per box)
        for (int j = tid; j < cnt * 21; j += 1024) {
            const int slot = j / 21;           // magic mul
            const int t    = j - slot * 21;
            const int n    = perm[ck + slot];
            if (t == 0) s_ob[slot] = (unsigned)(n * OUT_PER_BOX);

            const float y1 = boxes[n * 4 + 0];
            const float x1 = boxes[n * 4 + 1];
            const float y2 = boxes[n * 4 + 2];
            const float x2 = boxes[n * 4 + 3];

            if (t < CROP_H) {
                // exact fp32 RN, no FMA — must match numpy bitwise (validity
                // is a discontinuous function of in_y)
                const float hs   = __fdiv_rn(__fmul_rn(__fsub_rn(y2, y1), (float)(IMG_H - 1)),
                                             (float)(CROP_H - 1));
                const float in_y = __fadd_rn(__fmul_rn(y1, (float)(IMG_H - 1)),
                                             __fmul_rn((float)t, hs));
                const int vy = (in_y >= 0.0f) && (in_y <= (float)(IMG_H - 1));
                const float top = floorf(in_y);
                const float yw  = __fsub_rn(in_y, top);
                const int ti = (int)fminf(fmaxf(top, 0.0f), (float)(IMG_H - 1));
                const int r0 = min(ti, IMG_H - 2);
                const int sely = (ti == IMG_H - 1);
                f2u e; e.x = __int_as_float((r0 * IMG_W) | (sely << 14) | (vy << 15));
                e.y = yw;
                s_row[slot * CROP_H + t] = e;
            } else {
                const int xg = t - CROP_H;     // 0..6
                const float ws = __fdiv_rn(__fmul_rn(__fsub_rn(x2, x1), (float)(IMG_W - 1)),
                                           (float)(CROP_W - 1));
                const float x1W = __fmul_rn(x1, (float)(IMG_W - 1));
                f4u e;
                #pragma unroll
                for (int k = 0; k < 2; ++k) {
                    const int x = 2 * xg + k;
                    const float in_x = __fadd_rn(x1W, __fmul_rn((float)x, ws));
                    const int vx = (in_x >= 0.0f) && (in_x <= (float)(IMG_W - 1));
                    const float left = floorf(in_x);
                    const float xw   = __fsub_rn(in_x, left);
                    const int li = (int)fminf(fmaxf(left, 0.0f), (float)(IMG_W - 1));
                    const int c0 = min(li, IMG_W - 2);
                    const int selx = (li == IMG_W - 1);
                    const int bits = c0 | (selx << 8) | (vx << 9);
                    if (k == 0) { e.x = __int_as_float(bits); e.y = xw; }
                    else        { e.z = __int_as_float(bits); e.w = xw; }
                }
                s_colp[slot * 7 + xg] = e;
            }
        }
        __syncthreads();

        const int total = cnt * PAIRS;         // x-pair tasks in this chunk
        #pragma unroll 2
        for (int q = tid; q < total; q += 1024) {
            const int slot = q / PAIRS;        // magic mul
            const int rem  = q - slot * PAIRS;
            const int y    = rem / 7;          // magic mul
            const int xg   = rem - y * 7;

            const f2u re = s_row[slot * CROP_H + y];
            const f4u ce = s_colp[slot * 7 + xg];
            const int   ri = __float_as_int(re.x);
            const float yw = re.y;
            const int  offr = ri & 0x3FFF;
            const bool sely = (ri & 0x4000) != 0;
            const bool vy   = (ri & 0x8000) != 0;

            const int   ci0 = __float_as_int(ce.x);
            const float xw0 = ce.y;
            const int   ci1 = __float_as_int(ce.z);
            const float xw1 = ce.w;
            const int  base0 = offr + (ci0 & 0xFF);
            const int  base1 = offr + (ci1 & 0xFF);
            const bool sx0 = (ci0 & 0x100) != 0, v0 = vy && (ci0 & 0x200);
            const bool sx1 = (ci1 & 0x100) != 0, v1 = vy && (ci1 & 0x200);

            const unsigned outoff = s_ob[slot] + cbase + (unsigned)(y * CROP_W + 2 * xg);

            #pragma unroll
            for (int pc = 0; pc < 2; ++pc) {   // channel within the pair
                const float* __restrict__ P = s_plane + pc * PLANE;
                f2u res;
                {
                    const float a0 = P[base0], a1 = P[base0 + 1];
                    const float b0 = P[base0 + IMG_W], b1 = P[base0 + IMG_W + 1];
                    const float tA = sely ? b0 : a0;
                    const float tB = sely ? b1 : a1;
                    const float tl = sx0 ? tB : tA;
                    const float bl = sx0 ? b1 : b0;
                    const float top_v = __fadd_rn(tl, __fmul_rn(__fsub_rn(tB, tl), xw0));
                    const float bot_v = __fadd_rn(bl, __fmul_rn(__fsub_rn(b1, bl), xw0));
                    const float v = __fadd_rn(top_v, __fmul_rn(__fsub_rn(bot_v, top_v), yw));
                    res.x = v0 ? v : 0.0f;
                }
                {
                    const float a0 = P[base1], a1 = P[base1 + 1];
                    const float b0 = P[base1 + IMG_W], b1 = P[base1 + IMG_W + 1];
                    const float tA = sely ? b0 : a0;
                    const float tB = sely ? b1 : a1;
                    const float tl = sx1 ? tB : tA;
                    const float bl = sx1 ? b1 : b0;
                    const float top_v = __fadd_rn(tl, __fmul_rn(__fsub_rn(tB, tl), xw1));
                    const float bot_v = __fadd_rn(bl, __fmul_rn(__fsub_rn(b1, bl), xw1));
                    const float v = __fadd_rn(top_v, __fmul_rn(__fsub_rn(bot_v, top_v), yw));
                    res.y = v1 ? v : 0.0f;
                }
                *(f2u*)(out + (size_t)(outoff + (unsigned)(pc * POS))) = res;
            }
        }
    }
}

// ---------------------------------------------------------------------------
// Fallback (R5 structure, known 104 us) if workspace is too small.
// ---------------------------------------------------------------------------
__global__ __launch_bounds__(256) void crop_chw_kernel(
    const float* __restrict__ image,
    const float* __restrict__ boxes,
    const int* __restrict__ box_ind,
    float* __restrict__ out)
{
    const int bid  = blockIdx.x;
    const int cg   = bid & 7;
    const int n    = bid >> 3;
    const int tid  = threadIdx.x;
    if (tid >= POS) return;

    const int b = box_ind[n];
    const int y = tid / CROP_W;
    const int x = tid - y * CROP_W;

    const float y1 = boxes[n * 4 + 0];
    const float x1 = boxes[n * 4 + 1];
    const float y2 = boxes[n * 4 + 2];
    const float x2 = boxes[n * 4 + 3];

    const float hs   = __fdiv_rn(__fmul_rn(__fsub_rn(y2, y1), (float)(IMG_H - 1)),
                                 (float)(CROP_H - 1));
    const float in_y = __fadd_rn(__fmul_rn(y1, (float)(IMG_H - 1)),
                                 __fmul_rn((float)y, hs));
    const int vy = (in_y >= 0.0f) && (in_y <= (float)(IMG_H - 1));
    const float top = floorf(in_y);
    const float yw  = __fsub_rn(in_y, top);
    const int ti = (int)fminf(fmaxf(top, 0.0f), (float)(IMG_H - 1));

    const float ws   = __fdiv_rn(__fmul_rn(__fsub_rn(x2, x1), (float)(IMG_W - 1)),
                                 (float)(CROP_W - 1));
    const float in_x = __fadd_rn(__fmul_rn(x1, (float)(IMG_W - 1)),
                                 __fmul_rn((float)x, ws));
    const int vx = (in_x >= 0.0f) && (in_x <= (float)(IMG_W - 1));
    const float left = floorf(in_x);
    const float xw   = __fsub_rn(in_x, left);
    const int li = (int)fminf(fmaxf(left, 0.0f), (float)(IMG_W - 1));

    const int r0 = min(ti, IMG_H - 2);
    const int c0 = min(li, IMG_W - 2);
    const bool sely = (ti == IMG_H - 1);
    const bool selx = (li == IMG_W - 1);
    const bool vald = (vy & vx) != 0;

    const float* __restrict__ pl =
        image + (size_t)b * (size_t)(IMG_C * PLANE)
              + (size_t)(cg * CG) * PLANE + (r0 * IMG_W + c0);
    float* __restrict__ po =
        out + (size_t)n * (size_t)OUT_PER_BOX + (size_t)(cg * CG) * POS + tid;

    #pragma unroll 8
    for (int cl = 0; cl < CG; ++cl) {
        const float2 ra = *(const float2*)(pl);
        const float2 rb = *(const float2*)(pl + IMG_W);
        const float tA = sely ? rb.x : ra.x;
        const float tB = sely ? rb.y : ra.y;
        const float tl = selx ? tB : tA;
        const float bl = selx ? rb.y : rb.x;
        const float top_v = __fadd_rn(tl, __fmul_rn(__fsub_rn(tB, tl), xw));
        const float bot_v = __fadd_rn(bl, __fmul_rn(__fsub_rn(rb.y, bl), xw));
        const float v = __fadd_rn(top_v, __fmul_rn(__fsub_rn(bot_v, top_v), yw));
        *po = vald ? v : 0.0f;
        pl += PLANE;
        po += POS;
    }
}

extern "C" void kernel_launch(void* const* d_in, const int* in_sizes, int n_in,
                              void* d_out, int out_size, void* d_ws, size_t ws_size,
                              hipStream_t stream) {
    const float* image  = (const float*)d_in[0];
    const float* boxes  = (const float*)d_in[1];
    const int*   boxind = (const int*)d_in[2];
    float* out = (float*)d_out;

    const size_t need = (NBOX + IMG_B + 1) * sizeof(int);
    if (ws_size >= need) {
        int* perm    = (int*)d_ws;
        int* offsets = perm + NBOX;

        sort_boxes_kernel<<<1, 1024, 0, stream>>>(boxind, perm, offsets);
        CropAndResize_16630113370849_kernel<<<dim3(NCP, IMG_B), 1024, 0, stream>>>(
            image, boxes, perm, offsets, out);
    } else {
        crop_chw_kernel<<<dim3(NBOX * NCG), 256, 0, stream>>>(
            image, boxes, boxind, out);
    }
}

// Round 12
// 98.727 us; speedup vs baseline: 1.0366x; 1.0366x over previous
//
#include <hip/hip_runtime.h>

#define CROP_H 14
#define CROP_W 14
#define IMG_B 8
#define IMG_C 256
#define IMG_H 100
#define IMG_W 152
#define NBOX 1000
#define PLANE (IMG_H * IMG_W)                 // 15200
#define ZOFF  PLANE                           // zero-region base in LDS plane
#define POS (CROP_H * CROP_W)                 // 196
#define PAIRS (POS / 2)                       // 98 x-pair tasks per box
#define OUT_PER_BOX (IMG_C * POS)             // 50176
#define BOXCAP 64                             // boxes per param chunk
#define CG 32                                 // fallback path
#define NCG (IMG_C / CG)

typedef float f2u __attribute__((ext_vector_type(2), aligned(8)));
typedef float f4u __attribute__((ext_vector_type(4), aligned(16)));

// ---------------------------------------------------------------------------
// Kernel A: stable counting-sort of boxes by box_ind -> perm + per-image
// offsets. Deterministic (atomicOr order-independent, popcount ranks).
// ---------------------------------------------------------------------------
__global__ __launch_bounds__(1024) void sort_boxes_kernel(
    const int* __restrict__ box_ind,
    int* __restrict__ perm,
    int* __restrict__ offsets)            // [IMG_B + 1]
{
    __shared__ unsigned s_mask[IMG_B][32];
    __shared__ int s_tot[IMG_B];
    const int tid = threadIdx.x;

    if (tid < IMG_B * 32) ((unsigned*)s_mask)[tid] = 0u;
    __syncthreads();

    int key = 0;
    if (tid < NBOX) {
        key = box_ind[tid];
        atomicOr(&s_mask[key][tid >> 5], 1u << (tid & 31));
    }
    __syncthreads();

    if (tid < IMG_B) {
        int t = 0;
        #pragma unroll
        for (int w = 0; w < 32; ++w) t += __popc(s_mask[tid][w]);
        s_tot[tid] = t;
    }
    __syncthreads();

    if (tid == 0) {
        int acc = 0;
        #pragma unroll
        for (int k = 0; k < IMG_B; ++k) { offsets[k] = acc; acc += s_tot[k]; }
        offsets[IMG_B] = acc;
    }

    if (tid < NBOX) {
        int base = 0;
        #pragma unroll
        for (int k = 0; k < IMG_B; ++k) base += (k < key) ? s_tot[k] : 0;
        const int w = tid >> 5, b = tid & 31;
        int r = __popc(s_mask[key][w] & ((b == 0) ? 0u : ((1u << b) - 1u)));
        for (int ww = 0; ww < w; ++ww) r += __popc(s_mask[key][ww]);
        perm[base + r] = tid;
    }
}

// ---------------------------------------------------------------------------
// Kernel B: plane-in-LDS crop-and-resize, branch/select-free inner loop.
//  - clamp-by-weight: right/bottom clamp cases set lerp weight to 1.0 so the
//    generic 2x2 lerp reproduces the clamped value (<=1 ulp error).
//  - validity-by-address: invalid rows/cols encode base ZOFF; off=min(...)
//    lands in a zeroed LDS region -> output exactly 0.0. No masks, no selects.
//  - inner lerp contractible -> FMA. ~10 VALU + 2 ds_read2 per output.
// Block = (channel, image), 1024 threads, ~76 KB LDS -> 2 blocks/CU.
// ---------------------------------------------------------------------------
__global__ __launch_bounds__(1024, 8) void CropAndResize_16630113370849_kernel(
    const float* __restrict__ image,
    const float* __restrict__ boxes,
    const int* __restrict__ perm,
    const int* __restrict__ offsets,
    float* __restrict__ out)
{
    __shared__ __align__(16) float s_plane[15360];   // 15200 + 154 zeros (+pad)
    __shared__ f2u s_row[BOXCAP * CROP_H];   // {int rb (r0*152 or ZOFF), yw'}
    __shared__ f4u s_colp[BOXCAP * 7];       // {int cb0, xw0', int cb1, xw1'}
    __shared__ unsigned s_ob[BOXCAP];        // n * OUT_PER_BOX

    const int c   = blockIdx.x;              // channel 0..255
    const int b   = blockIdx.y;              // image 0..7
    const int tid = threadIdx.x;

    // stage plane (3800 float4, coalesced) + zero region
    {
        const float4* __restrict__ src =
            (const float4*)(image + ((size_t)b * IMG_C + c) * PLANE);
        float4* dst = (float4*)s_plane;
        #pragma unroll
        for (int i = 0; i < 4; ++i) {
            const int e = i * 1024 + tid;
            if (e < PLANE / 4) dst[e] = src[e];
        }
        if (tid < 160) s_plane[ZOFF + tid] = 0.0f;
    }

    const int s0 = offsets[b], s1 = offsets[b + 1];
    const unsigned cPOS = (unsigned)(c * POS);

    for (int ck = s0; ck < s1; ck += BOXCAP) {
        const int cnt = min(BOXCAP, s1 - ck);

        __syncthreads();   // plane ready (1st iter) / prev chunk readers done

        // setup: cnt*21 tasks (14 rows + 7 col-pairs per box)
        for (int j = tid; j < cnt * 21; j += 1024) {
            const int slot = j / 21;           // magic mul
            const int t    = j - slot * 21;
            const int n    = perm[ck + slot];
            if (t == 0) s_ob[slot] = (unsigned)(n * OUT_PER_BOX);

            const float y1 = boxes[n * 4 + 0];
            const float x1 = boxes[n * 4 + 1];
            const float y2 = boxes[n * 4 + 2];
            const float x2 = boxes[n * 4 + 3];

            if (t < CROP_H) {
                // exact fp32 RN, no FMA — must match numpy bitwise (validity
                // is a discontinuous function of in_y)
                const float hs   = __fdiv_rn(__fmul_rn(__fsub_rn(y2, y1), (float)(IMG_H - 1)),
                                             (float)(CROP_H - 1));
                const float in_y = __fadd_rn(__fmul_rn(y1, (float)(IMG_H - 1)),
                                             __fmul_rn((float)t, hs));
                const int vy = (in_y >= 0.0f) && (in_y <= (float)(IMG_H - 1));
                const float top = floorf(in_y);
                const float yw  = __fsub_rn(in_y, top);
                const int ti = (int)fminf(fmaxf(top, 0.0f), (float)(IMG_H - 1));
                const int r0 = min(ti, IMG_H - 2);
                const bool sely = (ti == IMG_H - 1);
                f2u e;
                e.x = __int_as_float(vy ? (r0 * IMG_W) : ZOFF);
                e.y = sely ? 1.0f : yw;        // clamp-by-weight
                s_row[slot * CROP_H + t] = e;
            } else {
                const int xg = t - CROP_H;     // 0..6
                const float ws = __fdiv_rn(__fmul_rn(__fsub_rn(x2, x1), (float)(IMG_W - 1)),
                                           (float)(CROP_W - 1));
                const float x1W = __fmul_rn(x1, (float)(IMG_W - 1));
                f4u e;
                #pragma unroll
                for (int k = 0; k < 2; ++k) {
                    const int x = 2 * xg + k;
                    const float in_x = __fadd_rn(x1W, __fmul_rn((float)x, ws));
                    const int vx = (in_x >= 0.0f) && (in_x <= (float)(IMG_W - 1));
                    const float left = floorf(in_x);
                    const float xw   = __fsub_rn(in_x, left);
                    const int li = (int)fminf(fmaxf(left, 0.0f), (float)(IMG_W - 1));
                    const int c0 = min(li, IMG_W - 2);
                    const bool selx = (li == IMG_W - 1);
                    const int   cb  = vx ? c0 : ZOFF;
                    const float xwp = selx ? 1.0f : xw;   // clamp-by-weight
                    if (k == 0) { e.x = __int_as_float(cb); e.y = xwp; }
                    else        { e.z = __int_as_float(cb); e.w = xwp; }
                }
                s_colp[slot * 7 + xg] = e;
            }
        }
        __syncthreads();

        const int total = cnt * PAIRS;         // x-pair tasks in this chunk
        #pragma unroll 2
        for (int q = tid; q < total; q += 1024) {
            const int slot = q / PAIRS;        // magic mul
            const int rem  = q - slot * PAIRS;
            const int y    = rem / 7;          // magic mul
            const int xg   = rem - y * 7;

            const f2u re = s_row[slot * CROP_H + y];
            const f4u ce = s_colp[slot * 7 + xg];
            const int   rb  = __float_as_int(re.x);
            const float yw  = re.y;
            const int   cb0 = __float_as_int(ce.x);
            const float xw0 = ce.y;
            const int   cb1 = __float_as_int(ce.z);
            const float xw1 = ce.w;

            // any invalid row/col -> off caps at ZOFF -> reads zeros -> 0.0
            const int off0 = min(rb + cb0, ZOFF);
            const int off1 = min(rb + cb1, ZOFF);

            const float* __restrict__ p0 = s_plane + off0;
            const float* __restrict__ p1 = s_plane + off1;

            // contractible lerps (FMA ok: continuous path, sub-ulp effect)
            const float a0 = p0[0], a1 = p0[1];
            const float b0 = p0[IMG_W], b1 = p0[IMG_W + 1];
            const float t0 = a0 + (a1 - a0) * xw0;
            const float u0 = b0 + (b1 - b0) * xw0;
            const float v0 = t0 + (u0 - t0) * yw;

            const float c0_ = p1[0], c1_ = p1[1];
            const float d0_ = p1[IMG_W], d1_ = p1[IMG_W + 1];
            const float t1 = c0_ + (c1_ - c0_) * xw1;
            const float u1 = d0_ + (d1_ - d0_) * xw1;
            const float v1 = t1 + (u1 - t1) * yw;

            f2u res; res.x = v0; res.y = v1;
            *(f2u*)(out + (size_t)(s_ob[slot] + cPOS + (unsigned)(2 * rem))) = res;
        }
    }
}

// ---------------------------------------------------------------------------
// Fallback (R5 structure, known 104 us) if workspace is too small.
// ---------------------------------------------------------------------------
__global__ __launch_bounds__(256) void crop_chw_kernel(
    const float* __restrict__ image,
    const float* __restrict__ boxes,
    const int* __restrict__ box_ind,
    float* __restrict__ out)
{
    const int bid  = blockIdx.x;
    const int cg   = bid & 7;
    const int n    = bid >> 3;
    const int tid  = threadIdx.x;
    if (tid >= POS) return;

    const int b = box_ind[n];
    const int y = tid / CROP_W;
    const int x = tid - y * CROP_W;

    const float y1 = boxes[n * 4 + 0];
    const float x1 = boxes[n * 4 + 1];
    const float y2 = boxes[n * 4 + 2];
    const float x2 = boxes[n * 4 + 3];

    const float hs   = __fdiv_rn(__fmul_rn(__fsub_rn(y2, y1), (float)(IMG_H - 1)),
                                 (float)(CROP_H - 1));
    const float in_y = __fadd_rn(__fmul_rn(y1, (float)(IMG_H - 1)),
                                 __fmul_rn((float)y, hs));
    const int vy = (in_y >= 0.0f) && (in_y <= (float)(IMG_H - 1));
    const float top = floorf(in_y);
    const float yw  = __fsub_rn(in_y, top);
    const int ti = (int)fminf(fmaxf(top, 0.0f), (float)(IMG_H - 1));

    const float ws   = __fdiv_rn(__fmul_rn(__fsub_rn(x2, x1), (float)(IMG_W - 1)),
                                 (float)(CROP_W - 1));
    const float in_x = __fadd_rn(__fmul_rn(x1, (float)(IMG_W - 1)),
                                 __fmul_rn((float)x, ws));
    const int vx = (in_x >= 0.0f) && (in_x <= (float)(IMG_W - 1));
    const float left = floorf(in_x);
    const float xw   = __fsub_rn(in_x, left);
    const int li = (int)fminf(fmaxf(left, 0.0f), (float)(IMG_W - 1));

    const int r0 = min(ti, IMG_H - 2);
    const int c0 = min(li, IMG_W - 2);
    const bool sely = (ti == IMG_H - 1);
    const bool selx = (li == IMG_W - 1);
    const bool vald = (vy & vx) != 0;

    const float* __restrict__ pl =
        image + (size_t)b * (size_t)(IMG_C * PLANE)
              + (size_t)(cg * CG) * PLANE + (r0 * IMG_W + c0);
    float* __restrict__ po =
        out + (size_t)n * (size_t)OUT_PER_BOX + (size_t)(cg * CG) * POS + tid;

    #pragma unroll 8
    for (int cl = 0; cl < CG; ++cl) {
        const float2 ra = *(const float2*)(pl);
        const float2 rb = *(const float2*)(pl + IMG_W);
        const float tA = sely ? rb.x : ra.x;
        const float tB = sely ? rb.y : ra.y;
        const float tl = selx ? tB : tA;
        const float bl = selx ? rb.y : rb.x;
        const float top_v = __fadd_rn(tl, __fmul_rn(__fsub_rn(tB, tl), xw));
        const float bot_v = __fadd_rn(bl, __fmul_rn(__fsub_rn(rb.y, bl), xw));
        const float v = __fadd_rn(top_v, __fmul_rn(__fsub_rn(bot_v, top_v), yw));
        *po = vald ? v : 0.0f;
        pl += PLANE;
        po += POS;
    }
}

extern "C" void kernel_launch(void* const* d_in, const int* in_sizes, int n_in,
                              void* d_out, int out_size, void* d_ws, size_t ws_size,
                              hipStream_t stream) {
    const float* image  = (const float*)d_in[0];
    const float* boxes  = (const float*)d_in[1];
    const int*   boxind = (const int*)d_in[2];
    float* out = (float*)d_out;

    const size_t need = (NBOX + IMG_B + 1) * sizeof(int);
    if (ws_size >= need) {
        int* perm    = (int*)d_ws;
        int* offsets = perm + NBOX;

        sort_boxes_kernel<<<1, 1024, 0, stream>>>(boxind, perm, offsets);
        CropAndResize_16630113370849_kernel<<<dim3(IMG_C, IMG_B), 1024, 0, stream>>>(
            image, boxes, perm, offsets, out);
    } else {
        crop_chw_kernel<<<dim3(NBOX * NCG), 256, 0, stream>>>(
            image, boxes, boxind, out);
    }
}